// Round 11
// baseline (42.882 us; speedup 1.0000x reference)
//
#include <hip/hip_runtime.h>

// CapsLayer2D, Gram-matrix MFMA version, f16 hi/lo single-MFMA predictions.
// dims: brc = B*R*C = 1024, I=128, DIN=16, K=32, DOUT=16.
// inputs: x [1024,128,16] f32; W [32,128,16,16] f32; out [1024,32,16] f32.
//
// Math (verified r3/r5/r6/r10): routing with uniform b0 collapses to
//   s0 = colsum(res)/128; G = res^T res (16x16, symmetric);
//   Krylov: K1 = G s0, K2 = G K1; s2 = s0 + (sg0+sg1) K1 + sg0 sg1 K2;
//   out = s2 * squash_scale(|s2|^2).
//
// Prediction trick (verified r5): x = xh + xl (f16 hi/lo). A-frag = [xh|xl]
// (K 0-15 = xh, 16-31 = xl); B-frag = [W|W] (lanes 32-63 read the SAME
// addresses as 0-31 -> coalesced dedup). One mfma_f32_16x16x32_f16 = x·W.
//
// Round-11 delta: x-fragment construction FUSED into the main kernel.
// Each wave builds its 16 af frags in-register from raw x using the r9-
// verified slot map (lane l <- 32B at brc=tile*16+(l&15), dhalf=(l>>4)&1,
// hi/lo = l>>4<2). Eliminates the 8MB xf write + 8MB read-back and the
// prepass->main serialization for x. Prepass = W-job only (2MB, ws 4MB).
// Phase A/B + Krylov epilogue byte-identical to round-10 (31.27us, passed).

using f32x4 = __attribute__((ext_vector_type(4))) float;
using h16x8 = __attribute__((ext_vector_type(8))) _Float16;

// res_lds element (i,o) at offset (i>>5)*544 + ((i>>3)&3)*136 + o*8 + (i&7)
constexpr int BRCS = 2184;   // halves per brc row (4*544 + pad)

constexpr size_t WFRAG_N = 32UL * 128 * 32 * 8;  // halves: W frags (2 MB)
constexpr size_t WS_NEEDED = WFRAG_N * 2;        // 4 MB

// ---------------- pre-pass: build f16 W fragment array (W-job only) -------
__global__ __launch_bounds__(256)
void prepass(const float* __restrict__ W, _Float16* __restrict__ wf) {
    const int tid = blockIdx.x * 256 + threadIdx.x;
    if (tid < 131072) {
        // thread -> (k, i, s); 32 slots/i: col o = s&15, d = 8*(s>>4)+e.
        const int s = tid & 31, i = (tid >> 5) & 127, k = tid >> 12;
        const int o = s & 15, dbase = 8 * (s >> 4);
        h16x8 wv;
#pragma unroll
        for (int e = 0; e < 8; ++e)
            wv[e] = (_Float16)W[(((size_t)k * 128 + i) * 16 + dbase + e) * 16 + o];
        *(h16x8*)(wf + ((size_t)(k * 128 + i) * 32 + s) * 8) = wv;
    }
}

// DPP helpers: sum over each 16-lane row (all lanes end with the row sum).
template <int CTRL>
__device__ inline float dpp_add(float x) {
    int v = __builtin_amdgcn_update_dpp(
        0, __builtin_bit_cast(int, x), CTRL, 0xf, 0xf, true);
    return x + __builtin_bit_cast(float, v);
}
__device__ inline float row16_sum(float x) {
    x = dpp_add<0xB1>(x);    // quad_perm(1,0,3,2)  : xor 1
    x = dpp_add<0x4E>(x);    // quad_perm(2,3,0,1)  : xor 2
    x = dpp_add<0x141>(x);   // row_half_mirror     : xor 7 within 8
    x = dpp_add<0x140>(x);   // row_mirror          : xor 15 within 16
    return x;
}

// squash scale from |s|^2: (n/(1+n)) / sqrt(n+eps), via raw rcp/rsq.
__device__ inline float squash_scale(float n) {
    float rcp, rsq;
    asm("v_rcp_f32 %0, %1" : "=v"(rcp) : "v"(1.0f + n));
    asm("v_rsq_f32 %0, %1" : "=v"(rsq) : "v"(n + 1e-7f));
    return n * rcp * rsq;
}

// ---------------- main: MFMA res + Gram routing ----------------
__global__ __launch_bounds__(512, 4)
void caps_g4(const float* __restrict__ x, const _Float16* __restrict__ wf,
             float* __restrict__ out) {
    __shared__ _Float16 res_lds[16 * BRCS];   // 69,888 B -> 2 blocks/CU
    const int tid  = threadIdx.x;
    const int lane = tid & 63;
    const int w    = tid >> 6;            // wave 0..7, owns i = 16w..16w+15
    const int kq   = blockIdx.x >> 6;     // 0..7 (4 k's each)
    const int tile = blockIdx.x & 63;     // consecutive blocks share kq

    const int q  = lane & 15;             // col (o) / A-row (brc)
    const int hq = lane >> 4;             // 0..3
    const int hl = hq & 1;

    // ---- build this wave's 16 x A-frags in-register (r9-verified slot map):
    // lane l -> slot l of frag (tile, w*16+ii): 32B at brc=tile*16+(l&15),
    // d-half = (l>>4)&1; slots 0-31 hold xh, 32-63 hold xl.
    h16x8 af[16];
    {
        const float* xp = x + (size_t)(tile * 16 + q) * 2048
                            + (size_t)(w * 16) * 16 + 8 * hl;
#pragma unroll
        for (int ii = 0; ii < 16; ++ii) {
            const float* p = xp + ii * 16;
            float4 v0 = *(const float4*)p, v1 = *(const float4*)(p + 4);
            float v[8] = {v0.x, v0.y, v0.z, v0.w, v1.x, v1.y, v1.z, v1.w};
            h16x8 hi, lo;
#pragma unroll
            for (int e = 0; e < 8; ++e) {
                hi[e] = (_Float16)v[e];
                lo[e] = (_Float16)(v[e] - (float)hi[e]);
            }
            af[ii] = (hq < 2) ? hi : lo;  // uniform per 16-lane group
        }
    }

    h16x8 ones;
#pragma unroll
    for (int e = 0; e < 8; ++e) ones[e] = (_Float16)1.0f;

    for (int kk = 0; kk < 4; ++kk) {
        const int k = kq * 4 + kk;
        if (kk) __syncthreads();          // prev k's res_lds readers done

        // ---- phase A: res[i][brc][o] -> LDS f16 ----
        {
            // B-frag: slot (16*hl + q); lanes 32-63 read same addr as 0-31.
            const _Float16* wb = wf + (size_t)k * 32768 + (size_t)(16 * hl + q) * 8
                                    + (size_t)(w * 16) * 256;
#pragma unroll
            for (int s8 = 0; s8 < 2; ++s8) {   // super-groups of 8 i
                f32x4 ac[8];
#pragma unroll
                for (int m = 0; m < 8; ++m) {
                    const int ii = s8 * 8 + m;
                    h16x8 b = *(const h16x8*)(wb + (size_t)ii * 256);
                    f32x4 z = {0.f, 0.f, 0.f, 0.f};
                    ac[m] = __builtin_amdgcn_mfma_f32_16x16x32_f16(af[ii], b, z,
                                                                   0, 0, 0);
                }
                const int i0 = w * 16 + s8 * 8;
                const int cb = (i0 >> 5) * 544 + ((i0 >> 3) & 3) * 136 + q * 8;
#pragma unroll
                for (int r = 0; r < 4; ++r) {
                    // C layout: col = lane&15 (o), row = 4*(lane>>4)+r (brc)
                    h16x8 hv = {(_Float16)ac[0][r], (_Float16)ac[1][r],
                                (_Float16)ac[2][r], (_Float16)ac[3][r],
                                (_Float16)ac[4][r], (_Float16)ac[5][r],
                                (_Float16)ac[6][r], (_Float16)ac[7][r]};
                    *(h16x8*)&res_lds[(4 * hq + r) * BRCS + cb] = hv;
                }
            }
        }
        __syncthreads();

        // ---- phase B: per task (brc,k): G = res^T res, s0 = colsum/128 ----
#pragma unroll
        for (int t = 0; t < 2; ++t) {
            const int brc = 2 * w + t;
            f32x4 g4 = {0.f, 0.f, 0.f, 0.f};   // G[4hq+p][q]
            f32x4 s4 = {0.f, 0.f, 0.f, 0.f};   // colsum[q]
            const _Float16* rp = &res_lds[brc * BRCS + hq * 136 + q * 8];
#pragma unroll
            for (int c = 0; c < 4; ++c) {
                h16x8 f = *(const h16x8*)(rp + c * 544);
                g4 = __builtin_amdgcn_mfma_f32_16x16x32_f16(f, f, g4, 0, 0, 0);
                s4 = __builtin_amdgcn_mfma_f32_16x16x32_f16(ones, f, s4, 0, 0, 0);
            }

            // ---- Krylov epilogue (r10 verified) ----
            float s0 = s4[0] * 0.0078125f;

            // K1 = G s0 (G symmetric; lane sums its 4 rows, reduce over hq)
            float a0 = __shfl(s0, 4 * hq + 0), a1 = __shfl(s0, 4 * hq + 1);
            float a2 = __shfl(s0, 4 * hq + 2), a3 = __shfl(s0, 4 * hq + 3);
            float pp = fmaf(g4[0], a0, fmaf(g4[1], a1,
                       fmaf(g4[2], a2, g4[3] * a3)));
            pp += __shfl_xor(pp, 16); pp += __shfl_xor(pp, 32);
            const float K1 = pp;

            // K2 = G K1 (no squash in between)
            a0 = __shfl(K1, 4 * hq + 0); a1 = __shfl(K1, 4 * hq + 1);
            a2 = __shfl(K1, 4 * hq + 2); a3 = __shfl(K1, 4 * hq + 3);
            pp = fmaf(g4[0], a0, fmaf(g4[1], a1,
                 fmaf(g4[2], a2, g4[3] * a3)));
            pp += __shfl_xor(pp, 16); pp += __shfl_xor(pp, 32);
            const float K2 = pp;

            // 6 independent dots (parallel DPP chains)
            const float d00 = row16_sum(s0 * s0);
            const float d01 = row16_sum(s0 * K1);
            const float d02 = row16_sum(s0 * K2);
            const float d11 = row16_sum(K1 * K1);
            const float d12 = row16_sum(K1 * K2);
            const float d22 = row16_sum(K2 * K2);

            // scalar chain (no cross-lane)
            const float sg0 = squash_scale(d00);
            const float n1  = fmaf(sg0, fmaf(sg0, d11, 2.0f * d01), d00);
            const float sg1 = squash_scale(n1);
            const float beta = sg0 + sg1;
            const float gam  = sg0 * sg1;
            const float n2 = d00 + beta * beta * d11 + gam * gam * d22
                           + 2.0f * (beta * d01 + gam * d02 + beta * gam * d12);
            const float sg2 = squash_scale(n2);

            if (hq == 0)
                out[(((size_t)(tile * 16 + brc)) * 32 + k) * 16 + q] =
                    (s0 + beta * K1 + gam * K2) * sg2;
        }
    }
}

// ---------------- fallback (round-1 fp32 kernel) if ws too small ----------------
constexpr int WSTRIDE = 260;

__global__ __launch_bounds__(256)
void caps_fused(const float* __restrict__ x,
                const float* __restrict__ W,
                float* __restrict__ out)
{
    __shared__ float wlds[32 * WSTRIDE];

    const int tid  = threadIdx.x;
    const int lane = tid & 63;
    const int wave = tid >> 6;

    const int b    = blockIdx.x;
    const int tq   = b & 15;
    const int kq   = (b >> 4) & 7;
    const int sg   = b >> 7;
    const int k    = (sg & 3) * 8 + kq;
    const int tile = (sg >> 2) * 16 + tq;

    const int brc0 = tile * 8 + wave * 2;
    const int il = lane & 31;
    const int oh = lane >> 5;
    const int ob = oh * 8;

    float res[2][4][8];
#pragma unroll
    for (int t = 0; t < 2; ++t)
#pragma unroll
        for (int r = 0; r < 4; ++r)
#pragma unroll
            for (int q = 0; q < 8; ++q) res[t][r][q] = 0.0f;

    const float* Wk = W + (size_t)k * (128 * 16 * 16);

#pragma unroll
    for (int c = 0; c < 4; ++c) {
        __syncthreads();
#pragma unroll
        for (int j = 0; j < 8; ++j) {
            const int e    = j * 1024 + tid * 4;
            const int irow = e >> 8;
            const int rem  = e & 255;
            *reinterpret_cast<float4*>(&wlds[irow * WSTRIDE + rem]) =
                *reinterpret_cast<const float4*>(&Wk[c * 8192 + e]);
        }
        __syncthreads();

        const int i = c * 32 + il;
        float xv[2][16];
#pragma unroll
        for (int t = 0; t < 2; ++t) {
            const float* xp = x + ((size_t)(brc0 + t) * 128 + i) * 16;
#pragma unroll
            for (int q4 = 0; q4 < 4; ++q4) {
                float4 v4 = *reinterpret_cast<const float4*>(&xp[q4 * 4]);
                xv[t][q4*4+0] = v4.x; xv[t][q4*4+1] = v4.y;
                xv[t][q4*4+2] = v4.z; xv[t][q4*4+3] = v4.w;
            }
        }
        const float* wrow = &wlds[il * WSTRIDE + ob];
#pragma unroll
        for (int d = 0; d < 16; ++d) {
            float4 wa = *reinterpret_cast<const float4*>(&wrow[d * 16]);
            float4 wb = *reinterpret_cast<const float4*>(&wrow[d * 16 + 4]);
            const float w8[8] = {wa.x, wa.y, wa.z, wa.w, wb.x, wb.y, wb.z, wb.w};
#pragma unroll
            for (int t = 0; t < 2; ++t)
#pragma unroll
                for (int q = 0; q < 8; ++q)
                    res[t][c][q] = fmaf(xv[t][d], w8[q], res[t][c][q]);
        }
    }

#pragma unroll
    for (int t = 0; t < 2; ++t) {
        float bb[4] = {1.0f/128.0f, 1.0f/128.0f, 1.0f/128.0f, 1.0f/128.0f};
        float v[8];
#pragma unroll
        for (int iter = 0; iter < 3; ++iter) {
            float s[8];
#pragma unroll
            for (int q = 0; q < 8; ++q) {
                s[q] = bb[0] * res[t][0][q];
#pragma unroll
                for (int r = 1; r < 4; ++r) s[q] = fmaf(bb[r], res[t][r][q], s[q]);
            }
#pragma unroll
            for (int m = 1; m <= 16; m <<= 1)
#pragma unroll
                for (int q = 0; q < 8; ++q) s[q] += __shfl_xor(s[q], m);
            float loc = 0.0f;
#pragma unroll
            for (int q = 0; q < 8; ++q) loc = fmaf(s[q], s[q], loc);
            const float sq = loc + __shfl_xor(loc, 32);
            const float scale = (sq / (1.0f + sq)) / sqrtf(sq + 1e-7f);
#pragma unroll
            for (int q = 0; q < 8; ++q) v[q] = s[q] * scale;
            if (iter < 2) {
#pragma unroll
                for (int r = 0; r < 4; ++r) {
                    float tp = 0.0f;
#pragma unroll
                    for (int q = 0; q < 8; ++q) tp = fmaf(res[t][r][q], v[q], tp);
                    bb[r] += tp + __shfl_xor(tp, 32);
                }
            }
        }
        if (il == 0) {
            float* op = out + ((size_t)(brc0 + t) * 32 + k) * 16 + ob;
            *reinterpret_cast<float4*>(&op[0]) = make_float4(v[0], v[1], v[2], v[3]);
            *reinterpret_cast<float4*>(&op[4]) = make_float4(v[4], v[5], v[6], v[7]);
        }
    }
}

extern "C" void kernel_launch(void* const* d_in, const int* in_sizes, int n_in,
                              void* d_out, int out_size, void* d_ws, size_t ws_size,
                              hipStream_t stream) {
    const float* x  = (const float*)d_in[0];
    const float* W  = (const float*)d_in[1];
    float* out      = (float*)d_out;
    if (ws_size >= WS_NEEDED && d_ws != nullptr) {
        _Float16* wf = (_Float16*)d_ws;
        hipLaunchKernelGGL(prepass, dim3(512), dim3(256), 0, stream, W, wf);
        hipLaunchKernelGGL(caps_g4, dim3(512), dim3(512), 0, stream, x, wf, out);
    } else {
        hipLaunchKernelGGL(caps_fused, dim3(4096), dim3(256), 0, stream, x, W, out);
    }
}

// Round 12
// 41.056 us; speedup vs baseline: 1.0445x; 1.0445x over previous
//
#include <hip/hip_runtime.h>

// CapsLayer2D, Gram-matrix MFMA version, f16 hi/lo single-MFMA predictions.
// dims: brc = B*R*C = 1024, I=128, DIN=16, K=32, DOUT=16.
// inputs: x [1024,128,16] f32; W [32,128,16,16] f32; out [1024,32,16] f32.
//
// Math (verified r3/r5/r6/r10): routing with uniform b0 collapses to
//   s0 = colsum(res)/128; G = res^T res (16x16, symmetric);
//   Krylov: K1 = G s0, K2 = G K1; s2 = s0 + (sg0+sg1) K1 + sg0 sg1 K2;
//   out = s2 * squash_scale(|s2|^2).
//
// Round-12 delta (structure, not instruction count): 8-brc blocks with
// DOUBLE-BUFFERED res_lds. Grid 1024 = 128 (8-brc tiles) x 8 kq. Per k-iter:
// phase A(k+1) -> buf[next] overlaps phase B(k) <- buf[cur]; ONE barrier per
// k (was 2). Each wave: 16 i in phase A (A-frag rows 8-15 garbage, never
// stored), ONE task (brc=w) in phase B. Same waves/CU (2 blocks x 8 waves),
// same LDS total (2 x 34,944). Phase-A MFMA count doubles (~+1us, accepted);
// wf re-reads double (L2-resident). af preload = r10 xf layout via slot
// remap row'=(l&7)+8*(t8&1). Prepass byte-identical to r9/r10.

using f32x4 = __attribute__((ext_vector_type(4))) float;
using h16x8 = __attribute__((ext_vector_type(8))) _Float16;

// res element (i,o) at offset (i>>5)*544 + ((i>>3)&3)*136 + o*8 + (i&7)
constexpr int BRCS = 2184;   // halves per brc row (4*544 + pad)

constexpr size_t XFRAG_N = 64UL * 128 * 64 * 8;  // halves: x frags (8 MB)
constexpr size_t WFRAG_N = 32UL * 128 * 32 * 8;  // halves: W frags (2 MB)
constexpr size_t WS_NEEDED = (XFRAG_N + WFRAG_N) * 2;  // 10 MB

// ---------------- pre-pass (verified r9/r10): f16 fragment arrays ---------
__global__ __launch_bounds__(256)
void prepass(const float* __restrict__ x, const float* __restrict__ W,
             _Float16* __restrict__ ws) {
    _Float16* xf = ws;
    _Float16* wf = ws + XFRAG_N;

    const int tid = blockIdx.x * 256 + threadIdx.x;

    if (tid < 524288) {
        const int l  = tid & 63;
        const int wi = tid >> 6;              // 0..8191 = tile16*128 + i
        const int j  = l >> 4;                // 0,1 hi ; 2,3 lo
        const int brc = (wi >> 7) * 16 + (l & 15);
        const float* p = x + (size_t)brc * 2048 + (wi & 127) * 16 + 8 * (j & 1);
        float4 v0 = *(const float4*)p, v1 = *(const float4*)(p + 4);
        float v[8] = {v0.x, v0.y, v0.z, v0.w, v1.x, v1.y, v1.z, v1.w};
        h16x8 hi, lo;
#pragma unroll
        for (int e = 0; e < 8; ++e) {
            hi[e] = (_Float16)v[e];
            lo[e] = (_Float16)(v[e] - (float)hi[e]);
        }
        h16x8 outv = (j < 2) ? hi : lo;       // uniform per 16-lane group
        *(h16x8*)(xf + (size_t)wi * 512 + l * 8) = outv;
    } else if (tid < 524288 + 131072) {
        // W job: thread -> (k, i, s); 32 slots/i: col o = s&15, d = 8*(s>>4)+e.
        const int t2 = tid - 524288;
        const int s = t2 & 31, i = (t2 >> 5) & 127, k = t2 >> 12;
        const int o = s & 15, dbase = 8 * (s >> 4);
        h16x8 wv;
#pragma unroll
        for (int e = 0; e < 8; ++e)
            wv[e] = (_Float16)W[(((size_t)k * 128 + i) * 16 + dbase + e) * 16 + o];
        *(h16x8*)(wf + ((size_t)(k * 128 + i) * 32 + s) * 8) = wv;
    }
}

// DPP helpers: sum over each 16-lane row (all lanes end with the row sum).
template <int CTRL>
__device__ inline float dpp_add(float x) {
    int v = __builtin_amdgcn_update_dpp(
        0, __builtin_bit_cast(int, x), CTRL, 0xf, 0xf, true);
    return x + __builtin_bit_cast(float, v);
}
__device__ inline float row16_sum(float x) {
    x = dpp_add<0xB1>(x);    // quad_perm(1,0,3,2)  : xor 1
    x = dpp_add<0x4E>(x);    // quad_perm(2,3,0,1)  : xor 2
    x = dpp_add<0x141>(x);   // row_half_mirror     : xor 7 within 8
    x = dpp_add<0x140>(x);   // row_mirror          : xor 15 within 16
    return x;
}

// squash scale from |s|^2: (n/(1+n)) / sqrt(n+eps), via raw rcp/rsq.
__device__ inline float squash_scale(float n) {
    float rcp, rsq;
    asm("v_rcp_f32 %0, %1" : "=v"(rcp) : "v"(1.0f + n));
    asm("v_rsq_f32 %0, %1" : "=v"(rsq) : "v"(n + 1e-7f));
    return n * rcp * rsq;
}

// ---------------- main: 8-brc blocks, double-buffered res ----------------
__global__ __launch_bounds__(512, 4)
void caps_g4(const _Float16* __restrict__ ws, float* __restrict__ out) {
    __shared__ _Float16 res_lds[2][8 * BRCS];   // 2 x 34,944 B -> 2 blocks/CU
    const _Float16* xf = ws;
    const _Float16* wf = ws + XFRAG_N;

    const int tid  = threadIdx.x;
    const int lane = tid & 63;
    const int w    = tid >> 6;            // wave 0..7: phase-A i = 16w..16w+15,
                                          //            phase-B task brc = w
    const int kq   = blockIdx.x >> 7;     // 0..7 (4 k's each)
    const int t8   = blockIdx.x & 127;    // 8-brc tile; blocks sharing kq adjacent

    const int q  = lane & 15;             // col (o) / A-row (brc)
    const int hq = lane >> 4;             // 0..3
    const int hl = hq & 1;
    const int half = t8 & 1;              // which half of the 16-brc xf tile

    // preload this wave's 16 x A-frags; rows 0-7 = brc t8*8..+7 (rows 8-15
    // duplicate them -> garbage C rows 8-15, never stored)
    h16x8 af[16];
    {
        const int slot = (lane & 48) | ((lane & 7) + 8 * half);
        const _Float16* xb = xf + (size_t)((t8 >> 1) * 128 + w * 16) * 512
                                + (size_t)slot * 8;
#pragma unroll
        for (int ii = 0; ii < 16; ++ii)
            af[ii] = *(const h16x8*)(xb + (size_t)ii * 512);
    }

    h16x8 ones;
#pragma unroll
    for (int e = 0; e < 8; ++e) ones[e] = (_Float16)1.0f;

    const int k0 = kq * 4;

    // ---- phase A into buf[cur]: res[i][brc(0-7)][o] ----
    auto phaseA = [&](int k, int cur) {
        const _Float16* wb = wf + (size_t)k * 32768 + (size_t)(16 * hl + q) * 8
                                + (size_t)(w * 16) * 256;
#pragma unroll
        for (int s8 = 0; s8 < 2; ++s8) {   // super-groups of 8 i
            f32x4 ac[8];
#pragma unroll
            for (int m = 0; m < 8; ++m) {
                const int ii = s8 * 8 + m;
                h16x8 b = *(const h16x8*)(wb + (size_t)ii * 256);
                f32x4 z = {0.f, 0.f, 0.f, 0.f};
                ac[m] = __builtin_amdgcn_mfma_f32_16x16x32_f16(af[ii], b, z,
                                                               0, 0, 0);
            }
            const int i0 = w * 16 + s8 * 8;
            const int cb = (i0 >> 5) * 544 + ((i0 >> 3) & 3) * 136 + q * 8;
            if (hq < 2) {                  // C rows 0-7 only (valid brc)
#pragma unroll
                for (int r = 0; r < 4; ++r) {
                    // C layout: col = lane&15 (o), row = 4*hq+r (brc)
                    h16x8 hv = {(_Float16)ac[0][r], (_Float16)ac[1][r],
                                (_Float16)ac[2][r], (_Float16)ac[3][r],
                                (_Float16)ac[4][r], (_Float16)ac[5][r],
                                (_Float16)ac[6][r], (_Float16)ac[7][r]};
                    *(h16x8*)&res_lds[cur][(4 * hq + r) * BRCS + cb] = hv;
                }
            }
        }
    };

    phaseA(k0, 0);
    __syncthreads();

    for (int kk = 0; kk < 4; ++kk) {
        const int cur = kk & 1;
        if (kk < 3) phaseA(k0 + kk + 1, cur ^ 1);   // overlaps phase B below

        // ---- phase B: task (brc = w, k = k0+kk) from buf[cur] ----
        {
            const int k = k0 + kk;
            f32x4 g4 = {0.f, 0.f, 0.f, 0.f};   // G[4hq+p][q]
            f32x4 s4 = {0.f, 0.f, 0.f, 0.f};   // colsum[q]
            const _Float16* rp = &res_lds[cur][w * BRCS + hq * 136 + q * 8];
#pragma unroll
            for (int c = 0; c < 4; ++c) {
                h16x8 f = *(const h16x8*)(rp + c * 544);
                g4 = __builtin_amdgcn_mfma_f32_16x16x32_f16(f, f, g4, 0, 0, 0);
                s4 = __builtin_amdgcn_mfma_f32_16x16x32_f16(ones, f, s4, 0, 0, 0);
            }

            // ---- Krylov epilogue (r10 verified) ----
            float s0 = s4[0] * 0.0078125f;

            float a0 = __shfl(s0, 4 * hq + 0), a1 = __shfl(s0, 4 * hq + 1);
            float a2 = __shfl(s0, 4 * hq + 2), a3 = __shfl(s0, 4 * hq + 3);
            float pp = fmaf(g4[0], a0, fmaf(g4[1], a1,
                       fmaf(g4[2], a2, g4[3] * a3)));
            pp += __shfl_xor(pp, 16); pp += __shfl_xor(pp, 32);
            const float K1 = pp;

            a0 = __shfl(K1, 4 * hq + 0); a1 = __shfl(K1, 4 * hq + 1);
            a2 = __shfl(K1, 4 * hq + 2); a3 = __shfl(K1, 4 * hq + 3);
            pp = fmaf(g4[0], a0, fmaf(g4[1], a1,
                 fmaf(g4[2], a2, g4[3] * a3)));
            pp += __shfl_xor(pp, 16); pp += __shfl_xor(pp, 32);
            const float K2 = pp;

            const float d00 = row16_sum(s0 * s0);
            const float d01 = row16_sum(s0 * K1);
            const float d02 = row16_sum(s0 * K2);
            const float d11 = row16_sum(K1 * K1);
            const float d12 = row16_sum(K1 * K2);
            const float d22 = row16_sum(K2 * K2);

            const float sg0 = squash_scale(d00);
            const float n1  = fmaf(sg0, fmaf(sg0, d11, 2.0f * d01), d00);
            const float sg1 = squash_scale(n1);
            const float beta = sg0 + sg1;
            const float gam  = sg0 * sg1;
            const float n2 = d00 + beta * beta * d11 + gam * gam * d22
                           + 2.0f * (beta * d01 + gam * d02 + beta * gam * d12);
            const float sg2 = squash_scale(n2);

            if (hq == 0)
                out[(((size_t)(t8 * 8 + w)) * 32 + k) * 16 + q] =
                    (s0 + beta * K1 + gam * K2) * sg2;
        }
        __syncthreads();   // buf[cur^1] writes done AND buf[cur] reads done
    }
}

// ---------------- fallback (round-1 fp32 kernel) if ws too small ----------------
constexpr int WSTRIDE = 260;

__global__ __launch_bounds__(256)
void caps_fused(const float* __restrict__ x,
                const float* __restrict__ W,
                float* __restrict__ out)
{
    __shared__ float wlds[32 * WSTRIDE];

    const int tid  = threadIdx.x;
    const int lane = tid & 63;
    const int wave = tid >> 6;

    const int b    = blockIdx.x;
    const int tq   = b & 15;
    const int kq   = (b >> 4) & 7;
    const int sg   = b >> 7;
    const int k    = (sg & 3) * 8 + kq;
    const int tile = (sg >> 2) * 16 + tq;

    const int brc0 = tile * 8 + wave * 2;
    const int il = lane & 31;
    const int oh = lane >> 5;
    const int ob = oh * 8;

    float res[2][4][8];
#pragma unroll
    for (int t = 0; t < 2; ++t)
#pragma unroll
        for (int r = 0; r < 4; ++r)
#pragma unroll
            for (int q = 0; q < 8; ++q) res[t][r][q] = 0.0f;

    const float* Wk = W + (size_t)k * (128 * 16 * 16);

#pragma unroll
    for (int c = 0; c < 4; ++c) {
        __syncthreads();
#pragma unroll
        for (int j = 0; j < 8; ++j) {
            const int e    = j * 1024 + tid * 4;
            const int irow = e >> 8;
            const int rem  = e & 255;
            *reinterpret_cast<float4*>(&wlds[irow * WSTRIDE + rem]) =
                *reinterpret_cast<const float4*>(&Wk[c * 8192 + e]);
        }
        __syncthreads();

        const int i = c * 32 + il;
        float xv[2][16];
#pragma unroll
        for (int t = 0; t < 2; ++t) {
            const float* xp = x + ((size_t)(brc0 + t) * 128 + i) * 16;
#pragma unroll
            for (int q4 = 0; q4 < 4; ++q4) {
                float4 v4 = *reinterpret_cast<const float4*>(&xp[q4 * 4]);
                xv[t][q4*4+0] = v4.x; xv[t][q4*4+1] = v4.y;
                xv[t][q4*4+2] = v4.z; xv[t][q4*4+3] = v4.w;
            }
        }
        const float* wrow = &wlds[il * WSTRIDE + ob];
#pragma unroll
        for (int d = 0; d < 16; ++d) {
            float4 wa = *reinterpret_cast<const float4*>(&wrow[d * 16]);
            float4 wb = *reinterpret_cast<const float4*>(&wrow[d * 16 + 4]);
            const float w8[8] = {wa.x, wa.y, wa.z, wa.w, wb.x, wb.y, wb.z, wb.w};
#pragma unroll
            for (int t = 0; t < 2; ++t)
#pragma unroll
                for (int q = 0; q < 8; ++q)
                    res[t][c][q] = fmaf(xv[t][d], w8[q], res[t][c][q]);
        }
    }

#pragma unroll
    for (int t = 0; t < 2; ++t) {
        float bb[4] = {1.0f/128.0f, 1.0f/128.0f, 1.0f/128.0f, 1.0f/128.0f};
        float v[8];
#pragma unroll
        for (int iter = 0; iter < 3; ++iter) {
            float s[8];
#pragma unroll
            for (int q = 0; q < 8; ++q) {
                s[q] = bb[0] * res[t][0][q];
#pragma unroll
                for (int r = 1; r < 4; ++r) s[q] = fmaf(bb[r], res[t][r][q], s[q]);
            }
#pragma unroll
            for (int m = 1; m <= 16; m <<= 1)
#pragma unroll
                for (int q = 0; q < 8; ++q) s[q] += __shfl_xor(s[q], m);
            float loc = 0.0f;
#pragma unroll
            for (int q = 0; q < 8; ++q) loc = fmaf(s[q], s[q], loc);
            const float sq = loc + __shfl_xor(loc, 32);
            const float scale = (sq / (1.0f + sq)) / sqrtf(sq + 1e-7f);
#pragma unroll
            for (int q = 0; q < 8; ++q) v[q] = s[q] * scale;
            if (iter < 2) {
#pragma unroll
                for (int r = 0; r < 4; ++r) {
                    float tp = 0.0f;
#pragma unroll
                    for (int q = 0; q < 8; ++q) tp = fmaf(res[t][r][q], v[q], tp);
                    bb[r] += tp + __shfl_xor(tp, 32);
                }
            }
        }
        if (il == 0) {
            float* op = out + ((size_t)(brc0 + t) * 32 + k) * 16 + ob;
            *reinterpret_cast<float4*>(&op[0]) = make_float4(v[0], v[1], v[2], v[3]);
            *reinterpret_cast<float4*>(&op[4]) = make_float4(v[4], v[5], v[6], v[7]);
        }
    }
}

extern "C" void kernel_launch(void* const* d_in, const int* in_sizes, int n_in,
                              void* d_out, int out_size, void* d_ws, size_t ws_size,
                              hipStream_t stream) {
    const float* x  = (const float*)d_in[0];
    const float* W  = (const float*)d_in[1];
    float* out      = (float*)d_out;
    if (ws_size >= WS_NEEDED && d_ws != nullptr) {
        _Float16* ws = (_Float16*)d_ws;
        hipLaunchKernelGGL(prepass, dim3(2560), dim3(256), 0, stream, x, W, ws);
        hipLaunchKernelGGL(caps_g4, dim3(1024), dim3(512), 0, stream, ws, out);
    } else {
        hipLaunchKernelGGL(caps_fused, dim3(4096), dim3(256), 0, stream, x, W, out);
    }
}

// Round 13
// 31.117 us; speedup vs baseline: 1.3781x; 1.3194x over previous
//
#include <hip/hip_runtime.h>

// CapsLayer2D, Gram-matrix MFMA version, f16 hi/lo single-MFMA predictions.
// dims: brc = B*R*C = 1024, I=128, DIN=16, K=32, DOUT=16.
// inputs: x [1024,128,16] f32; W [32,128,16,16] f32; out [1024,32,16] f32.
//
// FINAL (round-13) = exact round-10 configuration, the measured optimum
// (31.27us). History: r11 x-fusion +11.6us (scattered gathers + reg
// pressure); r12 double-buffer +9.8us (2x phase-A MFMA + 2x wf traffic
// outweigh barrier savings). Occupancy structurally capped (LDS 69.9KB ->
// 2 blocks/CU; VGPR<=128 -> 4 waves/SIMD); all tested levers beyond this
// config regressed or were flat.
//
// Math (verified r3/r5/r6/r10): routing with uniform b0 collapses to
//   s0 = colsum(res)/128; G = res^T res (16x16, symmetric);
//   Krylov: K1 = G s0, K2 = G K1; s2 = s0 + (sg0+sg1) K1 + sg0 sg1 K2;
//   out = s2 * squash_scale(|s2|^2).
//
// Prediction trick (verified r5): x = xh + xl (f16 hi/lo). A-frag = [xh|xl]
// (K 0-15 = xh, 16-31 = xl); B-frag = [W|W] (lanes 32-63 read the SAME
// addresses as 0-31 -> coalesced dedup). One mfma_f32_16x16x32_f16 = x·W.

using f32x4 = __attribute__((ext_vector_type(4))) float;
using h16x8 = __attribute__((ext_vector_type(8))) _Float16;

// res_lds element (i,o) at offset (i>>5)*544 + ((i>>3)&3)*136 + o*8 + (i&7)
constexpr int BRCS = 2184;   // halves per brc row (4*544 + pad)

constexpr size_t XFRAG_N = 64UL * 128 * 64 * 8;  // halves: x frags (8 MB)
constexpr size_t WFRAG_N = 32UL * 128 * 32 * 8;  // halves: W frags (2 MB)
constexpr size_t WS_NEEDED = (XFRAG_N + WFRAG_N) * 2;  // 10 MB

// ---------------- pre-pass: build f16 fragment arrays ----------------
// x-job (verified r9): wave wi = tid>>6 handles fragment (tile = wi>>7,
// i = wi&127); lane l -> slot l. Contiguous 1KB/wave stores.
__global__ __launch_bounds__(256)
void prepass(const float* __restrict__ x, const float* __restrict__ W,
             _Float16* __restrict__ ws) {
    _Float16* xf = ws;
    _Float16* wf = ws + XFRAG_N;

    const int tid = blockIdx.x * 256 + threadIdx.x;

    if (tid < 524288) {
        const int l  = tid & 63;
        const int wi = tid >> 6;              // 0..8191 = tile*128 + i
        const int j  = l >> 4;                // 0,1 hi ; 2,3 lo
        const int brc = (wi >> 7) * 16 + (l & 15);
        const float* p = x + (size_t)brc * 2048 + (wi & 127) * 16 + 8 * (j & 1);
        float4 v0 = *(const float4*)p, v1 = *(const float4*)(p + 4);
        float v[8] = {v0.x, v0.y, v0.z, v0.w, v1.x, v1.y, v1.z, v1.w};
        h16x8 hi, lo;
#pragma unroll
        for (int e = 0; e < 8; ++e) {
            hi[e] = (_Float16)v[e];
            lo[e] = (_Float16)(v[e] - (float)hi[e]);
        }
        h16x8 outv = (j < 2) ? hi : lo;       // uniform per 16-lane group
        *(h16x8*)(xf + (size_t)wi * 512 + l * 8) = outv;
    } else if (tid < 524288 + 131072) {
        // W job: thread -> (k, i, s); 32 slots/i: col o = s&15, d = 8*(s>>4)+e.
        const int t2 = tid - 524288;
        const int s = t2 & 31, i = (t2 >> 5) & 127, k = t2 >> 12;
        const int o = s & 15, dbase = 8 * (s >> 4);
        h16x8 wv;
#pragma unroll
        for (int e = 0; e < 8; ++e)
            wv[e] = (_Float16)W[(((size_t)k * 128 + i) * 16 + dbase + e) * 16 + o];
        *(h16x8*)(wf + ((size_t)(k * 128 + i) * 32 + s) * 8) = wv;
    }
}

// DPP helpers: sum over each 16-lane row (all lanes end with the row sum).
template <int CTRL>
__device__ inline float dpp_add(float x) {
    int v = __builtin_amdgcn_update_dpp(
        0, __builtin_bit_cast(int, x), CTRL, 0xf, 0xf, true);
    return x + __builtin_bit_cast(float, v);
}
__device__ inline float row16_sum(float x) {
    x = dpp_add<0xB1>(x);    // quad_perm(1,0,3,2)  : xor 1
    x = dpp_add<0x4E>(x);    // quad_perm(2,3,0,1)  : xor 2
    x = dpp_add<0x141>(x);   // row_half_mirror     : xor 7 within 8
    x = dpp_add<0x140>(x);   // row_mirror          : xor 15 within 16
    return x;
}

// squash scale from |s|^2: (n/(1+n)) / sqrt(n+eps), via raw rcp/rsq.
__device__ inline float squash_scale(float n) {
    float rcp, rsq;
    asm("v_rcp_f32 %0, %1" : "=v"(rcp) : "v"(1.0f + n));
    asm("v_rsq_f32 %0, %1" : "=v"(rsq) : "v"(n + 1e-7f));
    return n * rcp * rsq;
}

// ---------------- main: MFMA res + Gram routing ----------------
__global__ __launch_bounds__(512, 4)
void caps_g4(const _Float16* __restrict__ ws, float* __restrict__ out) {
    __shared__ _Float16 res_lds[16 * BRCS];   // 69,888 B -> 2 blocks/CU
    const _Float16* xf = ws;
    const _Float16* wf = ws + XFRAG_N;

    const int tid  = threadIdx.x;
    const int lane = tid & 63;
    const int w    = tid >> 6;            // wave 0..7, owns i = 16w..16w+15
    const int kq   = blockIdx.x >> 6;     // 0..7 (4 k's each)
    const int tile = blockIdx.x & 63;     // consecutive blocks share kq

    const int q  = lane & 15;             // col (o) / A-row (brc)
    const int hq = lane >> 4;             // 0..3
    const int hl = hq & 1;

    // preload this wave's 16 x A-frags ([xh|xl]), reused for all 4 k's
    h16x8 af[16];
    {
        const _Float16* xb = xf + (size_t)(tile * 128 + w * 16) * 512 + lane * 8;
#pragma unroll
        for (int ii = 0; ii < 16; ++ii)
            af[ii] = *(const h16x8*)(xb + (size_t)ii * 512);
    }

    h16x8 ones;
#pragma unroll
    for (int e = 0; e < 8; ++e) ones[e] = (_Float16)1.0f;

    for (int kk = 0; kk < 4; ++kk) {
        const int k = kq * 4 + kk;
        if (kk) __syncthreads();          // prev k's res_lds readers done

        // ---- phase A: res[i][brc][o] -> LDS f16 ----
        {
            // B-frag: slot (16*hl + q); lanes 32-63 read same addr as 0-31.
            const _Float16* wb = wf + (size_t)k * 32768 + (size_t)(16 * hl + q) * 8
                                    + (size_t)(w * 16) * 256;
#pragma unroll
            for (int s8 = 0; s8 < 2; ++s8) {   // super-groups of 8 i
                f32x4 ac[8];
#pragma unroll
                for (int m = 0; m < 8; ++m) {
                    const int ii = s8 * 8 + m;
                    h16x8 b = *(const h16x8*)(wb + (size_t)ii * 256);
                    f32x4 z = {0.f, 0.f, 0.f, 0.f};
                    ac[m] = __builtin_amdgcn_mfma_f32_16x16x32_f16(af[ii], b, z,
                                                                   0, 0, 0);
                }
                const int i0 = w * 16 + s8 * 8;
                const int cb = (i0 >> 5) * 544 + ((i0 >> 3) & 3) * 136 + q * 8;
#pragma unroll
                for (int r = 0; r < 4; ++r) {
                    // C layout: col = lane&15 (o), row = 4*(lane>>4)+r (brc)
                    h16x8 hv = {(_Float16)ac[0][r], (_Float16)ac[1][r],
                                (_Float16)ac[2][r], (_Float16)ac[3][r],
                                (_Float16)ac[4][r], (_Float16)ac[5][r],
                                (_Float16)ac[6][r], (_Float16)ac[7][r]};
                    *(h16x8*)&res_lds[(4 * hq + r) * BRCS + cb] = hv;
                }
            }
        }
        __syncthreads();

        // ---- phase B: per task (brc,k): G = res^T res, s0 = colsum/128 ----
#pragma unroll
        for (int t = 0; t < 2; ++t) {
            const int brc = 2 * w + t;
            f32x4 g4 = {0.f, 0.f, 0.f, 0.f};   // G[4hq+p][q]
            f32x4 s4 = {0.f, 0.f, 0.f, 0.f};   // colsum[q]
            const _Float16* rp = &res_lds[brc * BRCS + hq * 136 + q * 8];
#pragma unroll
            for (int c = 0; c < 4; ++c) {
                h16x8 f = *(const h16x8*)(rp + c * 544);
                g4 = __builtin_amdgcn_mfma_f32_16x16x32_f16(f, f, g4, 0, 0, 0);
                s4 = __builtin_amdgcn_mfma_f32_16x16x32_f16(ones, f, s4, 0, 0, 0);
            }

            // ---- Krylov epilogue (r10 verified) ----
            float s0 = s4[0] * 0.0078125f;

            // K1 = G s0 (G symmetric; lane sums its 4 rows, reduce over hq)
            float a0 = __shfl(s0, 4 * hq + 0), a1 = __shfl(s0, 4 * hq + 1);
            float a2 = __shfl(s0, 4 * hq + 2), a3 = __shfl(s0, 4 * hq + 3);
            float pp = fmaf(g4[0], a0, fmaf(g4[1], a1,
                       fmaf(g4[2], a2, g4[3] * a3)));
            pp += __shfl_xor(pp, 16); pp += __shfl_xor(pp, 32);
            const float K1 = pp;

            // K2 = G K1 (no squash in between)
            a0 = __shfl(K1, 4 * hq + 0); a1 = __shfl(K1, 4 * hq + 1);
            a2 = __shfl(K1, 4 * hq + 2); a3 = __shfl(K1, 4 * hq + 3);
            pp = fmaf(g4[0], a0, fmaf(g4[1], a1,
                 fmaf(g4[2], a2, g4[3] * a3)));
            pp += __shfl_xor(pp, 16); pp += __shfl_xor(pp, 32);
            const float K2 = pp;

            // 6 independent dots (parallel DPP chains)
            const float d00 = row16_sum(s0 * s0);
            const float d01 = row16_sum(s0 * K1);
            const float d02 = row16_sum(s0 * K2);
            const float d11 = row16_sum(K1 * K1);
            const float d12 = row16_sum(K1 * K2);
            const float d22 = row16_sum(K2 * K2);

            // scalar chain (no cross-lane)
            const float sg0 = squash_scale(d00);
            const float n1  = fmaf(sg0, fmaf(sg0, d11, 2.0f * d01), d00);
            const float sg1 = squash_scale(n1);
            const float beta = sg0 + sg1;
            const float gam  = sg0 * sg1;
            const float n2 = d00 + beta * beta * d11 + gam * gam * d22
                           + 2.0f * (beta * d01 + gam * d02 + beta * gam * d12);
            const float sg2 = squash_scale(n2);

            if (hq == 0)
                out[(((size_t)(tile * 16 + brc)) * 32 + k) * 16 + q] =
                    (s0 + beta * K1 + gam * K2) * sg2;
        }
    }
}

// ---------------- fallback (round-1 fp32 kernel) if ws too small ----------------
constexpr int WSTRIDE = 260;

__global__ __launch_bounds__(256)
void caps_fused(const float* __restrict__ x,
                const float* __restrict__ W,
                float* __restrict__ out)
{
    __shared__ float wlds[32 * WSTRIDE];

    const int tid  = threadIdx.x;
    const int lane = tid & 63;
    const int wave = tid >> 6;

    const int b    = blockIdx.x;
    const int tq   = b & 15;
    const int kq   = (b >> 4) & 7;
    const int sg   = b >> 7;
    const int k    = (sg & 3) * 8 + kq;
    const int tile = (sg >> 2) * 16 + tq;

    const int brc0 = tile * 8 + wave * 2;
    const int il = lane & 31;
    const int oh = lane >> 5;
    const int ob = oh * 8;

    float res[2][4][8];
#pragma unroll
    for (int t = 0; t < 2; ++t)
#pragma unroll
        for (int r = 0; r < 4; ++r)
#pragma unroll
            for (int q = 0; q < 8; ++q) res[t][r][q] = 0.0f;

    const float* Wk = W + (size_t)k * (128 * 16 * 16);

#pragma unroll
    for (int c = 0; c < 4; ++c) {
        __syncthreads();
#pragma unroll
        for (int j = 0; j < 8; ++j) {
            const int e    = j * 1024 + tid * 4;
            const int irow = e >> 8;
            const int rem  = e & 255;
            *reinterpret_cast<float4*>(&wlds[irow * WSTRIDE + rem]) =
                *reinterpret_cast<const float4*>(&Wk[c * 8192 + e]);
        }
        __syncthreads();

        const int i = c * 32 + il;
        float xv[2][16];
#pragma unroll
        for (int t = 0; t < 2; ++t) {
            const float* xp = x + ((size_t)(brc0 + t) * 128 + i) * 16;
#pragma unroll
            for (int q4 = 0; q4 < 4; ++q4) {
                float4 v4 = *reinterpret_cast<const float4*>(&xp[q4 * 4]);
                xv[t][q4*4+0] = v4.x; xv[t][q4*4+1] = v4.y;
                xv[t][q4*4+2] = v4.z; xv[t][q4*4+3] = v4.w;
            }
        }
        const float* wrow = &wlds[il * WSTRIDE + ob];
#pragma unroll
        for (int d = 0; d < 16; ++d) {
            float4 wa = *reinterpret_cast<const float4*>(&wrow[d * 16]);
            float4 wb = *reinterpret_cast<const float4*>(&wrow[d * 16 + 4]);
            const float w8[8] = {wa.x, wa.y, wa.z, wa.w, wb.x, wb.y, wb.z, wb.w};
#pragma unroll
            for (int t = 0; t < 2; ++t)
#pragma unroll
                for (int q = 0; q < 8; ++q)
                    res[t][c][q] = fmaf(xv[t][d], w8[q], res[t][c][q]);
        }
    }

#pragma unroll
    for (int t = 0; t < 2; ++t) {
        float bb[4] = {1.0f/128.0f, 1.0f/128.0f, 1.0f/128.0f, 1.0f/128.0f};
        float v[8];
#pragma unroll
        for (int iter = 0; iter < 3; ++iter) {
            float s[8];
#pragma unroll
            for (int q = 0; q < 8; ++q) {
                s[q] = bb[0] * res[t][0][q];
#pragma unroll
                for (int r = 1; r < 4; ++r) s[q] = fmaf(bb[r], res[t][r][q], s[q]);
            }
#pragma unroll
            for (int m = 1; m <= 16; m <<= 1)
#pragma unroll
                for (int q = 0; q < 8; ++q) s[q] += __shfl_xor(s[q], m);
            float loc = 0.0f;
#pragma unroll
            for (int q = 0; q < 8; ++q) loc = fmaf(s[q], s[q], loc);
            const float sq = loc + __shfl_xor(loc, 32);
            const float scale = (sq / (1.0f + sq)) / sqrtf(sq + 1e-7f);
#pragma unroll
            for (int q = 0; q < 8; ++q) v[q] = s[q] * scale;
            if (iter < 2) {
#pragma unroll
                for (int r = 0; r < 4; ++r) {
                    float tp = 0.0f;
#pragma unroll
                    for (int q = 0; q < 8; ++q) tp = fmaf(res[t][r][q], v[q], tp);
                    bb[r] += tp + __shfl_xor(tp, 32);
                }
            }
        }
        if (il == 0) {
            float* op = out + ((size_t)(brc0 + t) * 32 + k) * 16 + ob;
            *reinterpret_cast<float4*>(&op[0]) = make_float4(v[0], v[1], v[2], v[3]);
            *reinterpret_cast<float4*>(&op[4]) = make_float4(v[4], v[5], v[6], v[7]);
        }
    }
}

extern "C" void kernel_launch(void* const* d_in, const int* in_sizes, int n_in,
                              void* d_out, int out_size, void* d_ws, size_t ws_size,
                              hipStream_t stream) {
    const float* x  = (const float*)d_in[0];
    const float* W  = (const float*)d_in[1];
    float* out      = (float*)d_out;
    if (ws_size >= WS_NEEDED && d_ws != nullptr) {
        _Float16* ws = (_Float16*)d_ws;
        hipLaunchKernelGGL(prepass, dim3(2560), dim3(256), 0, stream, x, W, ws);
        hipLaunchKernelGGL(caps_g4, dim3(512),  dim3(512), 0, stream, ws, out);
    } else {
        hipLaunchKernelGGL(caps_fused, dim3(4096), dim3(256), 0, stream, x, W, out);
    }
}